// Round 12
// baseline (248.847 us; speedup 1.0000x reference)
//
#include <hip/hip_runtime.h>
#include <hip/hip_fp16.h>

// MPNN, 3 layers, N=50000, E=800000, D=64.
//   hx[d] = x[d] + sum_{e: dst=d} x[src_e]            (slab gather, fp16 data, fp32 accum)
//   out   = relu([hx | x] @ Wt^T + bu + (deg+1)*dvec) (fp16 MFMA, fp32 accum)
// Wt[n][k] = k<64 ? (Wm@Wu_top)[k][n] : Wu_bot[k-64][n]   (fp16, precomputed)
//
// Learned constraints:
//  - NO min-waves launch bound on register-heavy kernels (r4: spill to scratch).
//  - Do NOT fuse latency-bound gather with the MFMA update (r9: +47us/layer).
//  - MFMA A/B share the (g=lane>>4, j) -> k map: feeding both with f(g,j)=8g+j
//    (contiguous 16B) computes exact A*B. C/D: col=lane&15, row=4*(lane>>4)+reg.
//  - LDS A-tile rows stride 128B = same-bank; XOR-swizzle 16B-chunk ^= (row&7).
//  - Slab-CSR: slab[node*64+slot], slot=atomicAdd(cursor) in ONE pass; overflow
//    (deg>64, ~never) handled in-gather via ovf list scan (guarded by ovfcnt).
//  - Scattered commits from all XCDs amplify writes ~8x (r11: 50.8MB for a
//    6.4MB slab; one writeback per line per touching XCD). blockIdx%8 is NOT
//    the XCD map (r6->r7 delta was pure ushort). This round: TRUE XCD identity
//    via s_getreg(HW_REG_XCC_ID=20) + per-partition chunk tickets with
//    stealing (exactly-once regardless of what XCC_ID returns).
//  - rocprof per-dispatch us of tiny dispatches is serialization-inflated (r8).
//  - Per-lane arrays must be statically indexed or they spill to scratch.

#define DIM 64
// s_getreg imm: id=20 (XCC_ID, gfx940+), offset=0, width=4
#define XCC_GETREG_IMM (20 | (0 << 6) | ((4 - 1) << 11))

typedef _Float16 f16x8 __attribute__((ext_vector_type(8)));
typedef float f32x4 __attribute__((ext_vector_type(4)));

static __device__ __forceinline__ float lo16(unsigned u) {
  return __half2float(__ushort_as_half((unsigned short)(u & 0xFFFFu)));
}
static __device__ __forceinline__ float hi16(unsigned u) {
  return __half2float(__ushort_as_half((unsigned short)(u >> 16)));
}
static __device__ __forceinline__ unsigned pack16(float a, float b) {
  return (unsigned)__half_as_ushort(__float2half(a)) |
         ((unsigned)__half_as_ushort(__float2half(b)) << 16);
}

// blocks 0..2: fused fp16 weights per layer.  blocks 3..: zero cursor+ovfcnt+tickets.
__global__ __launch_bounds__(256) void fuse_weights_kernel(
    const float* __restrict__ Wm0, const float* __restrict__ bm0, const float* __restrict__ Wu0,
    const float* __restrict__ Wm1, const float* __restrict__ bm1, const float* __restrict__ Wu1,
    const float* __restrict__ Wm2, const float* __restrict__ bm2, const float* __restrict__ Wu2,
    unsigned short* __restrict__ Wtb, float* __restrict__ dv,
    int* __restrict__ cursor, int n) {
  const int l = blockIdx.x;
  if (l >= 3) {
    const int nq = (n >> 2) + 3;  // cursor[n] + ovfcnt + pad(3) + ticket[8]
    const int t0 = (l - 3) * 256 + threadIdx.x;
    const int stride = (gridDim.x - 3) * 256;
    int4* d4 = (int4*)cursor;
    for (int i = t0; i < nq; i += stride) d4[i] = make_int4(0, 0, 0, 0);
    return;
  }
  const float* Wm = l == 0 ? Wm0 : l == 1 ? Wm1 : Wm2;
  const float* bm = l == 0 ? bm0 : l == 1 ? bm1 : bm2;
  const float* Wu = l == 0 ? Wu0 : l == 1 ? Wu1 : Wu2;
  __shared__ float sWm[4096];
  __shared__ float sWu[4096];   // top half of Wu (rows 0..63)
  __shared__ float sW1[4096];   // Wm @ Wu_top
  const int tid = threadIdx.x;
  for (int i = tid; i < 4096; i += 256) {
    sWm[i] = Wm[i];
    sWu[i] = Wu[i];
  }
  __syncthreads();
  for (int i = tid; i < 4096; i += 256) {
    const int r = i >> 6, c = i & 63;
    float acc = 0.f;
#pragma unroll
    for (int k = 0; k < 64; ++k) acc = fmaf(sWm[r * 64 + k], sWu[k * 64 + c], acc);
    sW1[i] = acc;
  }
  __syncthreads();
  unsigned short* Wl = Wtb + (size_t)l * 8192;
  for (int i = tid; i < 8192; i += 256) {
    const int ncol = i >> 7, k = i & 127;
    const float v = (k < 64) ? sW1[k * 64 + ncol] : Wu[k * 64 + ncol];
    Wl[i] = __half_as_ushort(__float2half(v));
  }
  if (tid < 64) {
    float acc = 0.f;
#pragma unroll
    for (int k = 0; k < 64; ++k) acc = fmaf(bm[k], sWu[k * 64 + tid], acc);
    dv[l * 64 + tid] = acc;
  }
}

// One-pass prep: fp32->fp16 convert + slab-CSR build with XCD-owned partitions.
// Each block claims edge-chunks of its own XCD's dst-partition first (ticket
// per partition), then steals remaining partitions in rotated order.
__global__ __launch_bounds__(256) void prep_kernel(
    const float* __restrict__ x, unsigned* __restrict__ xb2, int nquads,
    const int* __restrict__ src, const int* __restrict__ dst,
    int* __restrict__ cursor, unsigned short* __restrict__ slab,
    unsigned* __restrict__ ovf, int* __restrict__ ovfcnt, int* __restrict__ ticket,
    int Epairs, int n, int Ecap) {
  const int gsz = gridDim.x * 256;
  for (int i = blockIdx.x * 256 + threadIdx.x; i < nquads; i += gsz) {
    const float4 v = ((const float4*)x)[i];
    xb2[2 * i] = pack16(v.x, v.y);
    xb2[2 * i + 1] = pack16(v.z, v.w);
  }
  const int xcc = __builtin_amdgcn_s_getreg(XCC_GETREG_IMM) & 7;  // locality hint only
  const int pn = (n + 7) / 8;          // nodes per partition
  const int CH = 2048;                 // edge-pairs per chunk
  const int nch = (Epairs + CH - 1) / CH;
  __shared__ int sC;
  for (int off = 0; off < 8; ++off) {
    const int p = (xcc + off) & 7;
    const int lo = p * pn;
    const int hi = (p == 7) ? n : lo + pn;
    while (true) {
      if (threadIdx.x == 0) sC = atomicAdd(&ticket[p], 1);
      __syncthreads();
      const int c = sC;
      __syncthreads();
      if (c >= nch) break;
      const int t1 = (c + 1) * CH < Epairs ? (c + 1) * CH : Epairs;
      for (int t = c * CH + threadIdx.x; t < t1; t += 256) {
        const int2 d2 = ((const int2*)dst)[t];
        if (d2.x >= lo && d2.x < hi) {
          const int p0 = atomicAdd(&cursor[d2.x], 1);
          const int s0 = src[2 * t];
          if (p0 < 64) {
            slab[(unsigned)d2.x * 64 + p0] = (unsigned short)s0;
          } else {
            const int o = atomicAdd(ovfcnt, 1);
            if (o < Ecap) ovf[o] = ((unsigned)d2.x << 16) | (unsigned)s0;
          }
        }
        if (d2.y >= lo && d2.y < hi) {
          const int p1 = atomicAdd(&cursor[d2.y], 1);
          const int s1 = src[2 * t + 1];
          if (p1 < 64) {
            slab[(unsigned)d2.y * 64 + p1] = (unsigned short)s1;
          } else {
            const int o = atomicAdd(ovfcnt, 1);
            if (o < Ecap) ovf[o] = ((unsigned)d2.y << 16) | (unsigned)s1;
          }
        }
      }
    }
  }
}

// One wave per node. Quarter-wave q=lane>>4 picks the neighbor; 16 lanes x
// uint2 (8B) = one 128B fp16 row -> 4 neighbor rows per load instruction.
// Index load is coalesced from slab[node*64+lane]. Overflow edges (deg>64,
// ovfcnt>0: ~never) are folded in via an ovf-list scan.
#define GRP(II)                                                        \
  {                                                                    \
    const int t0 = __builtin_amdgcn_readlane(myi, (II));               \
    const int t1 = __builtin_amdgcn_readlane(myi, (II) + 1);           \
    const int t2 = __builtin_amdgcn_readlane(myi, (II) + 2);           \
    const int t3 = __builtin_amdgcn_readlane(myi, (II) + 3);           \
    const int ta = (q & 1) ? t1 : t0;                                  \
    const int tb = (q & 1) ? t3 : t2;                                  \
    const int s = (q & 2) ? tb : ta;                                   \
    const uint2 u = xu2[(unsigned)s * 16 + j16];                       \
    a0 += lo16(u.x); a1 += hi16(u.x);                                  \
    a2 += lo16(u.y); a3 += hi16(u.y);                                  \
  }

__global__ __launch_bounds__(256, 8) void gather_kernel(
    const unsigned* __restrict__ xu,   // fp16 x, 32 uints/row
    const unsigned short* __restrict__ slab, const int* __restrict__ degp,
    const unsigned* __restrict__ ovf, const int* __restrict__ ovfcnt,
    unsigned* __restrict__ hxu, int n) {
  const int lane = threadIdx.x & 63;
  const int q = lane >> 4, j16 = lane & 15;
  const uint2* xu2 = (const uint2*)xu;
  uint2* hxu2 = (uint2*)hxu;
  const int ocnt = *ovfcnt;  // 0 in practice; uniform scalar
  const int wid = (blockIdx.x * 256 + threadIdx.x) >> 6;
  const int nwaves = (gridDim.x * 256) >> 6;
  for (int node = wid; node < n; node += nwaves) {
    const int nodeu = __builtin_amdgcn_readfirstlane(node);
    const int cnt = degp[nodeu];
    const int c64 = cnt > 64 ? 64 : cnt;
    int myi = 0;
    if (lane < c64) myi = (int)slab[(unsigned)nodeu * 64 + lane];
    float a0 = 0.f, a1 = 0.f, a2 = 0.f, a3 = 0.f;
    int i = 0;
    for (; i + 15 < c64; i += 16) {  // 4 loads in flight, 16 neighbors
      GRP(i) GRP(i + 4) GRP(i + 8) GRP(i + 12)
    }
    for (; i + 3 < c64; i += 4) { GRP(i) }
    const int rem = c64 - i;
    if (q < rem) { GRP(i) }            // readlanes past c64 unused by active lanes
    if (ocnt) {                        // overflow edges for this node (~never)
      for (int e = 0; e < ocnt; ++e) {
        const unsigned v = ovf[e];
        if ((int)(v >> 16) == nodeu && q == 0) {
          const uint2 u = xu2[(v & 0xFFFFu) * 16 + j16];
          a0 += lo16(u.x); a1 += hi16(u.x);
          a2 += lo16(u.y); a3 += hi16(u.y);
        }
      }
    }
    if (q == 0) {                      // self row
      const uint2 u = xu2[(unsigned)nodeu * 16 + j16];
      a0 += lo16(u.x); a1 += hi16(u.x);
      a2 += lo16(u.y); a3 += hi16(u.y);
    }
    a0 += __shfl_xor(a0, 16, 64); a0 += __shfl_xor(a0, 32, 64);
    a1 += __shfl_xor(a1, 16, 64); a1 += __shfl_xor(a1, 32, 64);
    a2 += __shfl_xor(a2, 16, 64); a2 += __shfl_xor(a2, 32, 64);
    a3 += __shfl_xor(a3, 16, 64); a3 += __shfl_xor(a3, 32, 64);
    if (q == 0)
      hxu2[(unsigned)nodeu * 16 + j16] = make_uint2(pack16(a0, a1), pack16(a2, a3));
  }
}

// 64 rows per block (4 waves x 16). A = [hx | x] (K=128) staged in swizzled
// LDS; B = Wt[n][k] fragments loaded as contiguous 16B; 16 MFMAs per wave.
template <int OUT_F32>
__global__ __launch_bounds__(256) void gemm_kernel(
    const unsigned short* __restrict__ hxb, const unsigned short* __restrict__ xb,
    const unsigned short* __restrict__ Wtb, const float* __restrict__ bu,
    const float* __restrict__ dvec, const int* __restrict__ deg,
    void* __restrict__ outp, int n) {
  __shared__ unsigned short lhx[64 * 64];
  __shared__ unsigned short lx[64 * 64];
  const int tid = threadIdx.x;
  const int base = blockIdx.x * 64;
  {
    const uint4* ghx = (const uint4*)hxb;
    const uint4* gx = (const uint4*)xb;
    uint4* shx = (uint4*)lhx;
    uint4* sx = (uint4*)lx;
    for (int t = tid; t < 512; t += 256) {
      const int row = t >> 3, c = t & 7;
      const int grow = base + row;
      uint4 vh = make_uint4(0, 0, 0, 0), vx = make_uint4(0, 0, 0, 0);
      if (grow < n) {
        vh = ghx[(size_t)grow * 8 + c];
        vx = gx[(size_t)grow * 8 + c];
      }
      const int cs = c ^ (row & 7);
      shx[row * 8 + cs] = vh;
      sx[row * 8 + cs] = vx;
    }
  }
  const int lane = tid & 63;
  const int w = tid >> 6;
  const int l15 = lane & 15, lg = lane >> 4;
  f16x8 bfr[16];
#pragma unroll
  for (int ct = 0; ct < 4; ++ct)
#pragma unroll
    for (int kq = 0; kq < 4; ++kq)
      bfr[ct * 4 + kq] = *(const f16x8*)((const char*)Wtb + (ct * 16 + l15) * 256 + kq * 64 + lg * 16);
  __syncthreads();
  f32x4 acc[4] = {0, 0, 0, 0};
  const int rt = w * 16 + l15;
#pragma unroll
  for (int kq = 0; kq < 4; ++kq) {
    const unsigned short* mat = (kq < 2) ? lhx : lx;
    const int chunk = lg + 4 * (kq & 1);
    const int cs = chunk ^ (rt & 7);
    const f16x8 af = *(const f16x8*)((const char*)mat + rt * 128 + cs * 16);
#pragma unroll
    for (int ct = 0; ct < 4; ++ct)
      acc[ct] = __builtin_amdgcn_mfma_f32_16x16x32_f16(af, bfr[ct * 4 + kq], acc[ct], 0, 0, 0);
  }
#pragma unroll
  for (int r = 0; r < 4; ++r) {
    const int row = base + w * 16 + lg * 4 + r;
    if (row < n) {
      const float dg = (float)(deg[row] + 1);
#pragma unroll
      for (int ct = 0; ct < 4; ++ct) {
        const int col = ct * 16 + l15;
        float v = acc[ct][r] + bu[col] + dg * dvec[col];
        v = v > 0.f ? v : 0.f;
        if (OUT_F32)
          ((float*)outp)[(size_t)row * 64 + col] = v;
        else
          ((unsigned short*)outp)[(size_t)row * 64 + col] = __half_as_ushort(__float2half(v));
      }
    }
  }
}

extern "C" void kernel_launch(void* const* d_in, const int* in_sizes, int n_in,
                              void* d_out, int out_size, void* d_ws, size_t ws_size,
                              hipStream_t stream) {
  const float* x = (const float*)d_in[0];
  const int* ei = (const int*)d_in[1];
  const int n = in_sizes[0] / DIM;   // 50000
  const int E = in_sizes[1] / 2;     // 800000
  const int* srcp = ei;
  const int* dstp = ei + E;

  // Workspace layout (16B alignment maintained; n%4==0, E even)
  unsigned short* xb = (unsigned short*)d_ws;        // n*64 fp16
  unsigned short* hxb = xb + (size_t)n * DIM;        // n*64 fp16
  unsigned short* yb = hxb + (size_t)n * DIM;        // n*64 fp16
  unsigned short* Wtb = yb + (size_t)n * DIM;        // 3*8192 fp16
  unsigned short* slab = Wtb + 3 * 8192;             // n*64 ushort
  float* dv = (float*)(slab + (size_t)n * DIM);      // 3*64
  int* cursor = (int*)(dv + 3 * 64);                 // n
  int* ovfcnt = cursor + n;                          // 1 (+3 pad)
  int* ticket = cursor + n + 4;                      // 8
  unsigned* ovf = (unsigned*)(ticket + 8);           // E

  // One-time prep: fused fp16 weights + zeroing (spare blocks); then one-pass
  // convert + XCD-owned slab-CSR build.
  fuse_weights_kernel<<<32, 256, 0, stream>>>(
      (const float*)d_in[2], (const float*)d_in[3], (const float*)d_in[4],
      (const float*)d_in[6], (const float*)d_in[7], (const float*)d_in[8],
      (const float*)d_in[10], (const float*)d_in[11], (const float*)d_in[12],
      Wtb, dv, cursor, n);
  const int nquads = n * DIM / 4;
  prep_kernel<<<1024, 256, 0, stream>>>(x, (unsigned*)xb, nquads, srcp, dstp,
                                        cursor, slab, ovf, ovfcnt, ticket, E / 2, n, E);

  // Layer chain (fp16): xb -> yb -> xb -> d_out(fp32)
  const int gblocks = (n + 63) / 64;
  gather_kernel<<<2048, 256, 0, stream>>>((const unsigned*)xb, slab, cursor, ovf, ovfcnt, (unsigned*)hxb, n);
  gemm_kernel<0><<<gblocks, 256, 0, stream>>>(hxb, xb, Wtb, (const float*)d_in[5], dv, cursor, yb, n);
  gather_kernel<<<2048, 256, 0, stream>>>((const unsigned*)yb, slab, cursor, ovf, ovfcnt, (unsigned*)hxb, n);
  gemm_kernel<0><<<gblocks, 256, 0, stream>>>(hxb, yb, Wtb + 8192, (const float*)d_in[9], dv + 64, cursor, xb, n);
  gather_kernel<<<2048, 256, 0, stream>>>((const unsigned*)xb, slab, cursor, ovf, ovfcnt, (unsigned*)hxb, n);
  gemm_kernel<1><<<gblocks, 256, 0, stream>>>(hxb, xb, Wtb + 16384, (const float*)d_in[13], dv + 128, cursor, d_out, n);
}

// Round 13
// 164.202 us; speedup vs baseline: 1.5155x; 1.5155x over previous
//
#include <hip/hip_runtime.h>
#include <hip/hip_fp16.h>

// MPNN, 3 layers, N=50000, E=800000, D=64.
//   hx[d] = x[d] + sum_{e: dst=d} x[src_e]            (slab gather, fp16 data, fp32 accum)
//   out   = relu([hx | x] @ Wt^T + bu + (deg+1)*dvec) (fp16 MFMA, fp32 accum)
// Wt[n][k] = k<64 ? (Wm@Wu_top)[k][n] : Wu_bot[k-64][n]   (fp16, precomputed)
//
// Learned constraints:
//  - NO min-waves launch bound on register-heavy kernels (r4: spill to scratch).
//  - Do NOT fuse latency-bound gather with the MFMA update (r9: +47us/layer).
//  - MFMA A/B share the (g=lane>>4, j) -> k map: feeding both with f(g,j)=8g+j
//    (contiguous 16B) computes exact A*B. C/D: col=lane&15, row=4*(lane>>4)+reg.
//  - LDS A-tile rows stride 128B = same-bank; XOR-swizzle 16B-chunk ^= (row&7).
//  - Slab-CSR in ONE pass (r11, 171us): slot=atomicAdd(cursor[dst]). Overflow
//    (slot>=62, ~never) via ovf list, folded into gather (guard: ovfcnt).
//  - r12 REGRESSION: XCC_ID ticket/steal partitioning cut WRITE 50.8->36.5MB
//    (locality direction correct) but per-chunk atomic+syncthreads serialized
//    the kernel: 70->137us. Lesson: never put barriers in the edge commit loop.
//  - This round: cursor EMBEDDED in the slab line ([int cursor][62 x ushort]
//    per 128B node block): kills cursor false sharing (was 16 nodes/line) and
//    makes the slot store hit the line the atomic just acquired.
//  - rocprof per-dispatch us of tiny dispatches is serialization-inflated (r8).
//  - Per-lane arrays must be statically indexed or they spill to scratch.

#define DIM 64

typedef _Float16 f16x8 __attribute__((ext_vector_type(8)));
typedef float f32x4 __attribute__((ext_vector_type(4)));

static __device__ __forceinline__ float lo16(unsigned u) {
  return __half2float(__ushort_as_half((unsigned short)(u & 0xFFFFu)));
}
static __device__ __forceinline__ float hi16(unsigned u) {
  return __half2float(__ushort_as_half((unsigned short)(u >> 16)));
}
static __device__ __forceinline__ unsigned pack16(float a, float b) {
  return (unsigned)__half_as_ushort(__float2half(a)) |
         ((unsigned)__half_as_ushort(__float2half(b)) << 16);
}

// blocks 0..2: fused fp16 weights per layer.  blocks 3..: zero embedded
// cursors (one int per 128B node block) + ovfcnt.
__global__ __launch_bounds__(256) void fuse_weights_kernel(
    const float* __restrict__ Wm0, const float* __restrict__ bm0, const float* __restrict__ Wu0,
    const float* __restrict__ Wm1, const float* __restrict__ bm1, const float* __restrict__ Wu1,
    const float* __restrict__ Wm2, const float* __restrict__ bm2, const float* __restrict__ Wu2,
    unsigned short* __restrict__ Wtb, float* __restrict__ dv,
    unsigned short* __restrict__ slab, int* __restrict__ ovfcnt, int n) {
  const int l = blockIdx.x;
  if (l >= 3) {
    const int t0 = (l - 3) * 256 + threadIdx.x;
    const int stride = (gridDim.x - 3) * 256;
    for (int i = t0; i < n; i += stride)
      *(int*)(slab + (size_t)i * 64) = 0;   // cursor at block head
    if (t0 == 0) *ovfcnt = 0;
    return;
  }
  const float* Wm = l == 0 ? Wm0 : l == 1 ? Wm1 : Wm2;
  const float* bm = l == 0 ? bm0 : l == 1 ? bm1 : bm2;
  const float* Wu = l == 0 ? Wu0 : l == 1 ? Wu1 : Wu2;
  __shared__ float sWm[4096];
  __shared__ float sWu[4096];   // top half of Wu (rows 0..63)
  __shared__ float sW1[4096];   // Wm @ Wu_top
  const int tid = threadIdx.x;
  for (int i = tid; i < 4096; i += 256) {
    sWm[i] = Wm[i];
    sWu[i] = Wu[i];
  }
  __syncthreads();
  for (int i = tid; i < 4096; i += 256) {
    const int r = i >> 6, c = i & 63;
    float acc = 0.f;
#pragma unroll
    for (int k = 0; k < 64; ++k) acc = fmaf(sWm[r * 64 + k], sWu[k * 64 + c], acc);
    sW1[i] = acc;
  }
  __syncthreads();
  unsigned short* Wl = Wtb + (size_t)l * 8192;
  for (int i = tid; i < 8192; i += 256) {
    const int ncol = i >> 7, k = i & 127;
    const float v = (k < 64) ? sW1[k * 64 + ncol] : Wu[k * 64 + ncol];
    Wl[i] = __half_as_ushort(__float2half(v));
  }
  if (tid < 64) {
    float acc = 0.f;
#pragma unroll
    for (int k = 0; k < 64; ++k) acc = fmaf(bm[k], sWu[k * 64 + tid], acc);
    dv[l * 64 + tid] = acc;
  }
}

// One-pass prep: fp32->fp16 convert of x + slab-CSR build (embedded cursor).
// No barriers, no partitioning in the commit loop (r12 lesson).
__global__ __launch_bounds__(256) void prep_kernel(
    const float* __restrict__ x, unsigned* __restrict__ xb2, int nquads,
    const int* __restrict__ src, const int* __restrict__ dst,
    unsigned short* __restrict__ slab,
    unsigned* __restrict__ ovf, int* __restrict__ ovfcnt, int Epairs, int Ecap) {
  const int gsz = gridDim.x * 256;
  for (int i = blockIdx.x * 256 + threadIdx.x; i < nquads; i += gsz) {
    const float4 v = ((const float4*)x)[i];
    xb2[2 * i] = pack16(v.x, v.y);
    xb2[2 * i + 1] = pack16(v.z, v.w);
  }
  for (int t = blockIdx.x * 256 + threadIdx.x; t < Epairs; t += gsz) {
    const int2 d2 = ((const int2*)dst)[t];
    const int2 s2 = ((const int2*)src)[t];
    const int p0 = atomicAdd((int*)(slab + (unsigned)d2.x * 64), 1);
    if (p0 < 62) {
      slab[(unsigned)d2.x * 64 + 2 + p0] = (unsigned short)s2.x;
    } else {
      const int o = atomicAdd(ovfcnt, 1);
      if (o < Ecap) ovf[o] = ((unsigned)d2.x << 16) | (unsigned)s2.x;
    }
    const int p1 = atomicAdd((int*)(slab + (unsigned)d2.y * 64), 1);
    if (p1 < 62) {
      slab[(unsigned)d2.y * 64 + 2 + p1] = (unsigned short)s2.y;
    } else {
      const int o = atomicAdd(ovfcnt, 1);
      if (o < Ecap) ovf[o] = ((unsigned)d2.y << 16) | (unsigned)s2.y;
    }
  }
}

// One wave per node. Quarter-wave q=lane>>4 picks the neighbor; 16 lanes x
// uint2 (8B) = one 128B fp16 row -> 4 neighbor rows per load instruction.
// Indices + deg come from the node's single 128B slab block.
#define GRP(II)                                                        \
  {                                                                    \
    const int t0 = __builtin_amdgcn_readlane(myi, (II));               \
    const int t1 = __builtin_amdgcn_readlane(myi, (II) + 1);           \
    const int t2 = __builtin_amdgcn_readlane(myi, (II) + 2);           \
    const int t3 = __builtin_amdgcn_readlane(myi, (II) + 3);           \
    const int ta = (q & 1) ? t1 : t0;                                  \
    const int tb = (q & 1) ? t3 : t2;                                  \
    const int s = (q & 2) ? tb : ta;                                   \
    const uint2 u = xu2[(unsigned)s * 16 + j16];                       \
    a0 += lo16(u.x); a1 += hi16(u.x);                                  \
    a2 += lo16(u.y); a3 += hi16(u.y);                                  \
  }

__global__ __launch_bounds__(256, 8) void gather_kernel(
    const unsigned* __restrict__ xu,   // fp16 x, 32 uints/row
    const unsigned short* __restrict__ slab,
    const unsigned* __restrict__ ovf, const int* __restrict__ ovfcnt,
    unsigned* __restrict__ hxu, int n) {
  const int lane = threadIdx.x & 63;
  const int q = lane >> 4, j16 = lane & 15;
  const uint2* xu2 = (const uint2*)xu;
  uint2* hxu2 = (uint2*)hxu;
  const int ocnt = *ovfcnt;  // 0 in practice; uniform scalar
  const int wid = (blockIdx.x * 256 + threadIdx.x) >> 6;
  const int nwaves = (gridDim.x * 256) >> 6;
  for (int node = wid; node < n; node += nwaves) {
    const int nodeu = __builtin_amdgcn_readfirstlane(node);
    const int cnt = *(const int*)(slab + (unsigned)nodeu * 64);  // embedded deg
    const int c62 = cnt > 62 ? 62 : cnt;
    int myi = 0;
    if (lane < c62) myi = (int)slab[(unsigned)nodeu * 64 + 2 + lane];
    float a0 = 0.f, a1 = 0.f, a2 = 0.f, a3 = 0.f;
    int i = 0;
    for (; i + 15 < c62; i += 16) {  // 4 loads in flight, 16 neighbors
      GRP(i) GRP(i + 4) GRP(i + 8) GRP(i + 12)
    }
    for (; i + 3 < c62; i += 4) { GRP(i) }
    const int rem = c62 - i;
    if (q < rem) { GRP(i) }            // inactive quarters add nothing
    if (ocnt) {                        // overflow edges (~never)
      for (int e = 0; e < ocnt; ++e) {
        const unsigned v = ovf[e];
        if ((int)(v >> 16) == nodeu && q == 0) {
          const uint2 u = xu2[(v & 0xFFFFu) * 16 + j16];
          a0 += lo16(u.x); a1 += hi16(u.x);
          a2 += lo16(u.y); a3 += hi16(u.y);
        }
      }
    }
    if (q == 0) {                      // self row
      const uint2 u = xu2[(unsigned)nodeu * 16 + j16];
      a0 += lo16(u.x); a1 += hi16(u.x);
      a2 += lo16(u.y); a3 += hi16(u.y);
    }
    a0 += __shfl_xor(a0, 16, 64); a0 += __shfl_xor(a0, 32, 64);
    a1 += __shfl_xor(a1, 16, 64); a1 += __shfl_xor(a1, 32, 64);
    a2 += __shfl_xor(a2, 16, 64); a2 += __shfl_xor(a2, 32, 64);
    a3 += __shfl_xor(a3, 16, 64); a3 += __shfl_xor(a3, 32, 64);
    if (q == 0)
      hxu2[(unsigned)nodeu * 16 + j16] = make_uint2(pack16(a0, a1), pack16(a2, a3));
  }
}

// 64 rows per block (4 waves x 16). A = [hx | x] (K=128) staged in swizzled
// LDS; B = Wt[n][k] fragments loaded as contiguous 16B; 16 MFMAs per wave.
// deg for the epilogue comes from the embedded slab cursor.
template <int OUT_F32>
__global__ __launch_bounds__(256) void gemm_kernel(
    const unsigned short* __restrict__ hxb, const unsigned short* __restrict__ xb,
    const unsigned short* __restrict__ Wtb, const float* __restrict__ bu,
    const float* __restrict__ dvec, const unsigned short* __restrict__ slab,
    void* __restrict__ outp, int n) {
  __shared__ unsigned short lhx[64 * 64];
  __shared__ unsigned short lx[64 * 64];
  const int tid = threadIdx.x;
  const int base = blockIdx.x * 64;
  {
    const uint4* ghx = (const uint4*)hxb;
    const uint4* gx = (const uint4*)xb;
    uint4* shx = (uint4*)lhx;
    uint4* sx = (uint4*)lx;
    for (int t = tid; t < 512; t += 256) {
      const int row = t >> 3, c = t & 7;
      const int grow = base + row;
      uint4 vh = make_uint4(0, 0, 0, 0), vx = make_uint4(0, 0, 0, 0);
      if (grow < n) {
        vh = ghx[(size_t)grow * 8 + c];
        vx = gx[(size_t)grow * 8 + c];
      }
      const int cs = c ^ (row & 7);
      shx[row * 8 + cs] = vh;
      sx[row * 8 + cs] = vx;
    }
  }
  const int lane = tid & 63;
  const int w = tid >> 6;
  const int l15 = lane & 15, lg = lane >> 4;
  f16x8 bfr[16];
#pragma unroll
  for (int ct = 0; ct < 4; ++ct)
#pragma unroll
    for (int kq = 0; kq < 4; ++kq)
      bfr[ct * 4 + kq] = *(const f16x8*)((const char*)Wtb + (ct * 16 + l15) * 256 + kq * 64 + lg * 16);
  __syncthreads();
  f32x4 acc[4] = {0, 0, 0, 0};
  const int rt = w * 16 + l15;
#pragma unroll
  for (int kq = 0; kq < 4; ++kq) {
    const unsigned short* mat = (kq < 2) ? lhx : lx;
    const int chunk = lg + 4 * (kq & 1);
    const int cs = chunk ^ (rt & 7);
    const f16x8 af = *(const f16x8*)((const char*)mat + rt * 128 + cs * 16);
#pragma unroll
    for (int ct = 0; ct < 4; ++ct)
      acc[ct] = __builtin_amdgcn_mfma_f32_16x16x32_f16(af, bfr[ct * 4 + kq], acc[ct], 0, 0, 0);
  }
#pragma unroll
  for (int r = 0; r < 4; ++r) {
    const int row = base + w * 16 + lg * 4 + r;
    if (row < n) {
      const float dg = (float)(*(const int*)(slab + (unsigned)row * 64) + 1);
#pragma unroll
      for (int ct = 0; ct < 4; ++ct) {
        const int col = ct * 16 + l15;
        float v = acc[ct][r] + bu[col] + dg * dvec[col];
        v = v > 0.f ? v : 0.f;
        if (OUT_F32)
          ((float*)outp)[(size_t)row * 64 + col] = v;
        else
          ((unsigned short*)outp)[(size_t)row * 64 + col] = __half_as_ushort(__float2half(v));
      }
    }
  }
}

extern "C" void kernel_launch(void* const* d_in, const int* in_sizes, int n_in,
                              void* d_out, int out_size, void* d_ws, size_t ws_size,
                              hipStream_t stream) {
  const float* x = (const float*)d_in[0];
  const int* ei = (const int*)d_in[1];
  const int n = in_sizes[0] / DIM;   // 50000
  const int E = in_sizes[1] / 2;     // 800000
  const int* srcp = ei;
  const int* dstp = ei + E;

  // Workspace layout (16B alignment maintained; n%4==0, E even)
  unsigned short* xb = (unsigned short*)d_ws;        // n*64 fp16
  unsigned short* hxb = xb + (size_t)n * DIM;        // n*64 fp16
  unsigned short* yb = hxb + (size_t)n * DIM;        // n*64 fp16
  unsigned short* Wtb = yb + (size_t)n * DIM;        // 3*8192 fp16
  unsigned short* slab = Wtb + 3 * 8192;             // n*64 ushort (128B blocks)
  float* dv = (float*)(slab + (size_t)n * DIM);      // 3*64
  int* ovfcnt = (int*)(dv + 3 * 64);                 // 1 (+3 pad)
  unsigned* ovf = (unsigned*)(ovfcnt + 4);           // E

  // One-time prep: fused fp16 weights + cursor zeroing (spare blocks);
  // then one-pass convert + slab-CSR build.
  fuse_weights_kernel<<<32, 256, 0, stream>>>(
      (const float*)d_in[2], (const float*)d_in[3], (const float*)d_in[4],
      (const float*)d_in[6], (const float*)d_in[7], (const float*)d_in[8],
      (const float*)d_in[10], (const float*)d_in[11], (const float*)d_in[12],
      Wtb, dv, slab, ovfcnt, n);
  const int nquads = n * DIM / 4;
  prep_kernel<<<1024, 256, 0, stream>>>(x, (unsigned*)xb, nquads, srcp, dstp,
                                        slab, ovf, ovfcnt, E / 2, E);

  // Layer chain (fp16): xb -> yb -> xb -> d_out(fp32)
  const int gblocks = (n + 63) / 64;
  gather_kernel<<<2048, 256, 0, stream>>>((const unsigned*)xb, slab, ovf, ovfcnt, (unsigned*)hxb, n);
  gemm_kernel<0><<<gblocks, 256, 0, stream>>>(hxb, xb, Wtb, (const float*)d_in[5], dv, slab, yb, n);
  gather_kernel<<<2048, 256, 0, stream>>>((const unsigned*)yb, slab, ovf, ovfcnt, (unsigned*)hxb, n);
  gemm_kernel<0><<<gblocks, 256, 0, stream>>>(hxb, yb, Wtb + 8192, (const float*)d_in[9], dv + 64, slab, xb, n);
  gather_kernel<<<2048, 256, 0, stream>>>((const unsigned*)xb, slab, ovf, ovfcnt, (unsigned*)hxb, n);
  gemm_kernel<1><<<gblocks, 256, 0, stream>>>(hxb, xb, Wtb + 16384, (const float*)d_in[13], dv + 128, slab, d_out, n);
}

// Round 14
// 146.639 us; speedup vs baseline: 1.6970x; 1.1198x over previous
//
#include <hip/hip_runtime.h>
#include <hip/hip_fp16.h>

// MPNN, 3 layers, N=50000, E=800000, D=64.
//   hx[d] = x[d] + sum_{e: dst=d} x[src_e]            (slab gather, fp16 data, fp32 accum)
//   out   = relu([hx | x] @ Wt^T + bu + (deg+1)*dvec) (fp16 MFMA, fp32 accum)
// Wt[n][k] = k<64 ? (Wm@Wu_top)[k][n] : Wu_bot[k-64][n]   (fp16, precomputed)
//
// Learned constraints:
//  - NO min-waves launch bound on register-heavy kernels (r4: spill to scratch).
//  - Do NOT fuse latency-bound gather with the MFMA update (r9: +47us/layer).
//  - MFMA A/B share the (g=lane>>4, j) -> k map: feeding both with f(g,j)=8g+j
//    (contiguous 16B) computes exact A*B. C/D: col=lane&15, row=4*(lane>>4)+reg.
//  - LDS A-tile rows stride 128B = same-bank; XOR-swizzle 16B-chunk ^= (row&7).
//  - Scattered commits to a small region from all XCDs amplify HBM writes ~8x
//    (r11/r13: 51MB for 6.4MB slab) and run at the ~1.2TB/s scattered-write
//    ceiling. Barriers/tickets in the commit loop are worse (r12: 70->137us).
//    THIS round's fix: two-phase bucket+fill. Bucket: block-private output
//    regions + LDS histogram/prefix (zero global atomics). Fill: one block
//    owns one 256-node partition, LDS cursors, single writeback per line.
//  - rocprof per-dispatch us of tiny dispatches is serialization-inflated (r8).
//  - Per-lane arrays must be statically indexed or they spill to scratch.

#define DIM 64
#define PN 256              // nodes per partition (dst>>8)
#define PAIRS_PER_BLK 1792  // 256 threads x 7 edge-pairs
#define EDGES_PER_BLK 3584
#define HDRW 200            // header stride in ushorts (197 used)

typedef _Float16 f16x8 __attribute__((ext_vector_type(8)));
typedef float f32x4 __attribute__((ext_vector_type(4)));

static __device__ __forceinline__ float lo16(unsigned u) {
  return __half2float(__ushort_as_half((unsigned short)(u & 0xFFFFu)));
}
static __device__ __forceinline__ float hi16(unsigned u) {
  return __half2float(__ushort_as_half((unsigned short)(u >> 16)));
}
static __device__ __forceinline__ unsigned pack16(float a, float b) {
  return (unsigned)__half_as_ushort(__float2half(a)) |
         ((unsigned)__half_as_ushort(__float2half(b)) << 16);
}

// blocks 0..2: fused fp16 weights per layer.  block 3: zero ovfcnt.
__global__ __launch_bounds__(256) void fuse_weights_kernel(
    const float* __restrict__ Wm0, const float* __restrict__ bm0, const float* __restrict__ Wu0,
    const float* __restrict__ Wm1, const float* __restrict__ bm1, const float* __restrict__ Wu1,
    const float* __restrict__ Wm2, const float* __restrict__ bm2, const float* __restrict__ Wu2,
    unsigned short* __restrict__ Wtb, float* __restrict__ dv, int* __restrict__ ovfcnt) {
  const int l = blockIdx.x;
  if (l >= 3) {
    if (threadIdx.x == 0) *ovfcnt = 0;
    return;
  }
  const float* Wm = l == 0 ? Wm0 : l == 1 ? Wm1 : Wm2;
  const float* bm = l == 0 ? bm0 : l == 1 ? bm1 : bm2;
  const float* Wu = l == 0 ? Wu0 : l == 1 ? Wu1 : Wu2;
  __shared__ float sWm[4096];
  __shared__ float sWu[4096];   // top half of Wu (rows 0..63)
  __shared__ float sW1[4096];   // Wm @ Wu_top
  const int tid = threadIdx.x;
  for (int i = tid; i < 4096; i += 256) {
    sWm[i] = Wm[i];
    sWu[i] = Wu[i];
  }
  __syncthreads();
  for (int i = tid; i < 4096; i += 256) {
    const int r = i >> 6, c = i & 63;
    float acc = 0.f;
#pragma unroll
    for (int k = 0; k < 64; ++k) acc = fmaf(sWm[r * 64 + k], sWu[k * 64 + c], acc);
    sW1[i] = acc;
  }
  __syncthreads();
  unsigned short* Wl = Wtb + (size_t)l * 8192;
  for (int i = tid; i < 8192; i += 256) {
    const int ncol = i >> 7, k = i & 127;
    const float v = (k < 64) ? sW1[k * 64 + ncol] : Wu[k * 64 + ncol];
    Wl[i] = __half_as_ushort(__float2half(v));
  }
  if (tid < 64) {
    float acc = 0.f;
#pragma unroll
    for (int k = 0; k < 64; ++k) acc = fmaf(bm[k], sWu[k * 64 + tid], acc);
    dv[l * 64 + tid] = acc;
  }
}

// Phase A: fp32->fp16 convert (grid-stride) + edge bucketing into block-private
// qbuf regions. LDS histogram + prefix; ZERO global atomics; deterministic
// capacity (block handles exactly EDGES_PER_BLK edges).
__global__ __launch_bounds__(256) void bucket_kernel(
    const float* __restrict__ x, unsigned* __restrict__ xb2, int nquads,
    const int* __restrict__ src, const int* __restrict__ dst,
    unsigned* __restrict__ qbuf, unsigned short* __restrict__ hdr,
    int Epairs, int NP) {
  const int gsz = gridDim.x * 256;
  const int t = threadIdx.x;
  for (int i = blockIdx.x * 256 + t; i < nquads; i += gsz) {
    const float4 v = ((const float4*)x)[i];
    xb2[2 * i] = pack16(v.x, v.y);
    xb2[2 * i + 1] = pack16(v.z, v.w);
  }
  __shared__ int hist[256];
  __shared__ int pref[256];
  __shared__ int sc[256];
  const int b = blockIdx.x;
  hist[t] = 0;
  __syncthreads();
  unsigned rec[14];
  int pr[14];
  const int base = b * PAIRS_PER_BLK;
#pragma unroll
  for (int k = 0; k < 7; ++k) {
    const int g = base + k * 256 + t;
    if (g < Epairs) {
      const int2 d2 = ((const int2*)dst)[g];
      const int2 s2 = ((const int2*)src)[g];
      const int p0 = d2.x >> 8;
      const int r0 = atomicAdd(&hist[p0], 1);
      pr[2 * k] = (p0 << 16) | r0;
      rec[2 * k] = ((unsigned)d2.x << 16) | (unsigned)(s2.x & 0xFFFF);
      const int p1 = d2.y >> 8;
      const int r1 = atomicAdd(&hist[p1], 1);
      pr[2 * k + 1] = (p1 << 16) | r1;
      rec[2 * k + 1] = ((unsigned)d2.y << 16) | (unsigned)(s2.y & 0xFFFF);
    } else {
      pr[2 * k] = -1;
      pr[2 * k + 1] = -1;
      rec[2 * k] = 0;
      rec[2 * k + 1] = 0;
    }
  }
  __syncthreads();
  const int myc = hist[t];
  sc[t] = myc;
  __syncthreads();
  for (int off = 1; off < 256; off <<= 1) {
    const int u = (t >= off) ? sc[t - off] : 0;
    __syncthreads();
    sc[t] += u;
    __syncthreads();
  }
  pref[t] = sc[t] - myc;  // exclusive prefix
  if (t < NP) hdr[(size_t)b * HDRW + t] = (unsigned short)pref[t];
  if (t == NP - 1) hdr[(size_t)b * HDRW + NP] = (unsigned short)sc[t];
  __syncthreads();
  unsigned* myq = qbuf + (size_t)b * EDGES_PER_BLK;
#pragma unroll
  for (int k = 0; k < 14; ++k) {
    if (pr[k] >= 0) myq[pref[pr[k] >> 16] + (pr[k] & 0xFFFF)] = rec[k];
  }
}

// Phase B: block p owns nodes [p*256, p*256+256): LDS cursors, no global
// atomics, every slab line written by exactly one block (one XCD).
__global__ __launch_bounds__(256) void fill_kernel(
    const unsigned* __restrict__ qbuf, const unsigned short* __restrict__ hdr,
    unsigned short* __restrict__ slab, unsigned* __restrict__ ovf,
    int* __restrict__ ovfcnt, int nblocksA, int n, int Ecap) {
  __shared__ int cur[256];
  const int p = blockIdx.x;
  const int t = threadIdx.x;
  cur[t] = 0;
  __syncthreads();
  for (int sb = t; sb < nblocksA; sb += 256) {
    const int s = hdr[(size_t)sb * HDRW + p];
    const int e = hdr[(size_t)sb * HDRW + p + 1];
    const unsigned* q = qbuf + (size_t)sb * EDGES_PER_BLK;
    for (int i = s; i < e; ++i) {
      const unsigned rec = q[i];
      const int d = rec >> 16;
      const int slot = atomicAdd(&cur[d & (PN - 1)], 1);
      if (slot < 62) {
        slab[(unsigned)d * 64 + 2 + slot] = (unsigned short)(rec & 0xFFFF);
      } else {
        const int o = atomicAdd(ovfcnt, 1);
        if (o < Ecap) ovf[o] = rec;
      }
    }
  }
  __syncthreads();
  const int node = p * PN + t;
  if (node < n) *(int*)(slab + (size_t)node * 64) = cur[t];
}

// One wave per node. Quarter-wave q picks the neighbor; 16 lanes x uint2 (8B)
// = one 128B fp16 row -> 4 neighbor rows per load instruction.
#define GRP(II)                                                        \
  {                                                                    \
    const int t0 = __builtin_amdgcn_readlane(myi, (II));               \
    const int t1 = __builtin_amdgcn_readlane(myi, (II) + 1);           \
    const int t2 = __builtin_amdgcn_readlane(myi, (II) + 2);           \
    const int t3 = __builtin_amdgcn_readlane(myi, (II) + 3);           \
    const int ta = (q & 1) ? t1 : t0;                                  \
    const int tb = (q & 1) ? t3 : t2;                                  \
    const int s = (q & 2) ? tb : ta;                                   \
    const uint2 u = xu2[(unsigned)s * 16 + j16];                       \
    a0 += lo16(u.x); a1 += hi16(u.x);                                  \
    a2 += lo16(u.y); a3 += hi16(u.y);                                  \
  }

__global__ __launch_bounds__(256, 8) void gather_kernel(
    const unsigned* __restrict__ xu,   // fp16 x, 32 uints/row
    const unsigned short* __restrict__ slab,
    const unsigned* __restrict__ ovf, const int* __restrict__ ovfcnt,
    unsigned* __restrict__ hxu, int n) {
  const int lane = threadIdx.x & 63;
  const int q = lane >> 4, j16 = lane & 15;
  const uint2* xu2 = (const uint2*)xu;
  uint2* hxu2 = (uint2*)hxu;
  const int ocnt = *ovfcnt;  // 0 in practice; uniform scalar
  const int wid = (blockIdx.x * 256 + threadIdx.x) >> 6;
  const int nwaves = (gridDim.x * 256) >> 6;
  for (int node = wid; node < n; node += nwaves) {
    const int nodeu = __builtin_amdgcn_readfirstlane(node);
    const int cnt = *(const int*)(slab + (unsigned)nodeu * 64);  // embedded deg
    const int c62 = cnt > 62 ? 62 : cnt;
    int myi = 0;
    if (lane < c62) myi = (int)slab[(unsigned)nodeu * 64 + 2 + lane];
    float a0 = 0.f, a1 = 0.f, a2 = 0.f, a3 = 0.f;
    int i = 0;
    for (; i + 15 < c62; i += 16) {  // 4 loads in flight, 16 neighbors
      GRP(i) GRP(i + 4) GRP(i + 8) GRP(i + 12)
    }
    for (; i + 3 < c62; i += 4) { GRP(i) }
    const int rem = c62 - i;
    if (q < rem) { GRP(i) }            // inactive quarters add nothing
    if (ocnt) {                        // overflow edges (~never)
      for (int e = 0; e < ocnt; ++e) {
        const unsigned v = ovf[e];
        if ((int)(v >> 16) == nodeu && q == 0) {
          const uint2 u = xu2[(v & 0xFFFFu) * 16 + j16];
          a0 += lo16(u.x); a1 += hi16(u.x);
          a2 += lo16(u.y); a3 += hi16(u.y);
        }
      }
    }
    if (q == 0) {                      // self row
      const uint2 u = xu2[(unsigned)nodeu * 16 + j16];
      a0 += lo16(u.x); a1 += hi16(u.x);
      a2 += lo16(u.y); a3 += hi16(u.y);
    }
    a0 += __shfl_xor(a0, 16, 64); a0 += __shfl_xor(a0, 32, 64);
    a1 += __shfl_xor(a1, 16, 64); a1 += __shfl_xor(a1, 32, 64);
    a2 += __shfl_xor(a2, 16, 64); a2 += __shfl_xor(a2, 32, 64);
    a3 += __shfl_xor(a3, 16, 64); a3 += __shfl_xor(a3, 32, 64);
    if (q == 0)
      hxu2[(unsigned)nodeu * 16 + j16] = make_uint2(pack16(a0, a1), pack16(a2, a3));
  }
}

// 64 rows per block (4 waves x 16). A = [hx | x] (K=128) staged in swizzled
// LDS; B = Wt[n][k] fragments loaded as contiguous 16B; 16 MFMAs per wave.
// deg for the epilogue comes from the embedded slab cursor.
template <int OUT_F32>
__global__ __launch_bounds__(256) void gemm_kernel(
    const unsigned short* __restrict__ hxb, const unsigned short* __restrict__ xb,
    const unsigned short* __restrict__ Wtb, const float* __restrict__ bu,
    const float* __restrict__ dvec, const unsigned short* __restrict__ slab,
    void* __restrict__ outp, int n) {
  __shared__ unsigned short lhx[64 * 64];
  __shared__ unsigned short lx[64 * 64];
  const int tid = threadIdx.x;
  const int base = blockIdx.x * 64;
  {
    const uint4* ghx = (const uint4*)hxb;
    const uint4* gx = (const uint4*)xb;
    uint4* shx = (uint4*)lhx;
    uint4* sx = (uint4*)lx;
    for (int t = tid; t < 512; t += 256) {
      const int row = t >> 3, c = t & 7;
      const int grow = base + row;
      uint4 vh = make_uint4(0, 0, 0, 0), vx = make_uint4(0, 0, 0, 0);
      if (grow < n) {
        vh = ghx[(size_t)grow * 8 + c];
        vx = gx[(size_t)grow * 8 + c];
      }
      const int cs = c ^ (row & 7);
      shx[row * 8 + cs] = vh;
      sx[row * 8 + cs] = vx;
    }
  }
  const int lane = tid & 63;
  const int w = tid >> 6;
  const int l15 = lane & 15, lg = lane >> 4;
  f16x8 bfr[16];
#pragma unroll
  for (int ct = 0; ct < 4; ++ct)
#pragma unroll
    for (int kq = 0; kq < 4; ++kq)
      bfr[ct * 4 + kq] = *(const f16x8*)((const char*)Wtb + (ct * 16 + l15) * 256 + kq * 64 + lg * 16);
  __syncthreads();
  f32x4 acc[4] = {0, 0, 0, 0};
  const int rt = w * 16 + l15;
#pragma unroll
  for (int kq = 0; kq < 4; ++kq) {
    const unsigned short* mat = (kq < 2) ? lhx : lx;
    const int chunk = lg + 4 * (kq & 1);
    const int cs = chunk ^ (rt & 7);
    const f16x8 af = *(const f16x8*)((const char*)mat + rt * 128 + cs * 16);
#pragma unroll
    for (int ct = 0; ct < 4; ++ct)
      acc[ct] = __builtin_amdgcn_mfma_f32_16x16x32_f16(af, bfr[ct * 4 + kq], acc[ct], 0, 0, 0);
  }
#pragma unroll
  for (int r = 0; r < 4; ++r) {
    const int row = base + w * 16 + lg * 4 + r;
    if (row < n) {
      const float dg = (float)(*(const int*)(slab + (unsigned)row * 64) + 1);
#pragma unroll
      for (int ct = 0; ct < 4; ++ct) {
        const int col = ct * 16 + l15;
        float v = acc[ct][r] + bu[col] + dg * dvec[col];
        v = v > 0.f ? v : 0.f;
        if (OUT_F32)
          ((float*)outp)[(size_t)row * 64 + col] = v;
        else
          ((unsigned short*)outp)[(size_t)row * 64 + col] = __half_as_ushort(__float2half(v));
      }
    }
  }
}

extern "C" void kernel_launch(void* const* d_in, const int* in_sizes, int n_in,
                              void* d_out, int out_size, void* d_ws, size_t ws_size,
                              hipStream_t stream) {
  const float* x = (const float*)d_in[0];
  const int* ei = (const int*)d_in[1];
  const int n = in_sizes[0] / DIM;   // 50000
  const int E = in_sizes[1] / 2;     // 800000
  const int* srcp = ei;
  const int* dstp = ei + E;
  const int Epairs = E / 2;
  const int NP = (n + PN - 1) / PN;                    // 196
  const int nblocksA = (Epairs + PAIRS_PER_BLK - 1) / PAIRS_PER_BLK;  // 224
  const int Ecap = E / 4;

  // Workspace layout (16B alignment maintained; n%4==0, E even)
  unsigned short* xb = (unsigned short*)d_ws;        // n*64 fp16
  unsigned short* hxb = xb + (size_t)n * DIM;        // n*64 fp16
  unsigned short* yb = hxb + (size_t)n * DIM;        // n*64 fp16
  unsigned short* Wtb = yb + (size_t)n * DIM;        // 3*8192 fp16
  unsigned short* slab = Wtb + 3 * 8192;             // n*64 ushort (128B blocks)
  float* dv = (float*)(slab + (size_t)n * DIM);      // 3*64
  int* ovfcnt = (int*)(dv + 3 * 64);                 // 1 (+3 pad)
  unsigned* ovf = (unsigned*)(ovfcnt + 4);           // Ecap
  unsigned* qbuf = ovf + Ecap;                       // nblocksA*EDGES_PER_BLK
  unsigned short* hdr = (unsigned short*)(qbuf + (size_t)nblocksA * EDGES_PER_BLK);  // nblocksA*HDRW

  // One-time prep: fused fp16 weights (+ovfcnt zero); bucket; fill.
  fuse_weights_kernel<<<4, 256, 0, stream>>>(
      (const float*)d_in[2], (const float*)d_in[3], (const float*)d_in[4],
      (const float*)d_in[6], (const float*)d_in[7], (const float*)d_in[8],
      (const float*)d_in[10], (const float*)d_in[11], (const float*)d_in[12],
      Wtb, dv, ovfcnt);
  const int nquads = n * DIM / 4;
  bucket_kernel<<<nblocksA, 256, 0, stream>>>(x, (unsigned*)xb, nquads, srcp, dstp,
                                              qbuf, hdr, Epairs, NP);
  fill_kernel<<<NP, 256, 0, stream>>>(qbuf, hdr, slab, ovf, ovfcnt, nblocksA, n, Ecap);

  // Layer chain (fp16): xb -> yb -> xb -> d_out(fp32)
  const int gblocks = (n + 63) / 64;
  gather_kernel<<<2048, 256, 0, stream>>>((const unsigned*)xb, slab, ovf, ovfcnt, (unsigned*)hxb, n);
  gemm_kernel<0><<<gblocks, 256, 0, stream>>>(hxb, xb, Wtb, (const float*)d_in[5], dv, slab, yb, n);
  gather_kernel<<<2048, 256, 0, stream>>>((const unsigned*)yb, slab, ovf, ovfcnt, (unsigned*)hxb, n);
  gemm_kernel<0><<<gblocks, 256, 0, stream>>>(hxb, yb, Wtb + 8192, (const float*)d_in[9], dv + 64, slab, xb, n);
  gather_kernel<<<2048, 256, 0, stream>>>((const unsigned*)xb, slab, ovf, ovfcnt, (unsigned*)hxb, n);
  gemm_kernel<1><<<gblocks, 256, 0, stream>>>(hxb, xb, Wtb + 16384, (const float*)d_in[13], dv + 128, slab, d_out, n);
}

// Round 18
// 124.779 us; speedup vs baseline: 1.9943x; 1.1752x over previous
//
#include <hip/hip_runtime.h>
#include <hip/hip_fp16.h>

// MPNN, 3 layers, N=50000, E=800000, D=64.
//   hx[d] = x[d] + sum_{e: dst=d} x[src_e]            (slab gather, fp16 data, fp32 accum)
//   out   = relu([hx | x] @ Wt^T + bu + (deg+1)*dvec) (fp16 MFMA, fp32 accum)
// Wt[n][k] = k<64 ? (Wm@Wu_top)[k][n] : Wu_bot[k-64][n]   (fp16, precomputed)
//
// Learned constraints:
//  - NO min-waves launch bound on register-heavy kernels (r4: spill to scratch).
//  - Do NOT fuse latency-bound gather with the MFMA update (r9: +47us/layer).
//  - MFMA A/B share the (g=lane>>4, j) -> k map: feeding both with f(g,j)=8g+j
//    (contiguous 16B) computes exact A*B. C/D: col=lane&15, row=4*(lane>>4)+reg.
//  - LDS A-tile rows stride 128B = same-bank; XOR-swizzle 16B-chunk ^= (row&7).
//  - Scattered commits from all XCDs amplify HBM writes ~8x; fix = two-phase
//    bucket(block-private regions, LDS hist/prefix, zero global atomics) +
//    fill(one block owns one 256-node partition, LDS cursors) (r14: -17us).
//    Tickets/barriers in the commit loop are worse (r12). blockIdx%8 != XCD.
//  - ds_bpermute RESPECTS EXEC on the SOURCE lane (returns 0 from inactive
//    lanes); v_readlane ignores exec. r16/r17 absmax~48 bug: divergent tail
//    `if (q<rem) bpermute` had inactive source lanes -> phantom node-0 row
//    added for every node with deg%4!=0. Fix: uniform `if(rem)` around the
//    bpermute (all 64 lanes execute it), divergent consume only.
//  - fp16 ACCUMULATION in gather: unproven (r16's failure was the bpermute
//    bug, but fp32 accum is known-good at absmax 4.0; keep fp32).
//  - rocprof per-dispatch us of tiny dispatches is serialization-inflated (r8).
//  - Per-lane arrays must be statically indexed or they spill to scratch.

#define DIM 64
#define PN 256              // nodes per partition (dst>>8)
#define PAIRS_PER_BLK 1792  // 256 threads x 7 edge-pairs
#define EDGES_PER_BLK 3584
#define HDRW 200            // header stride in ushorts (197 used)

typedef _Float16 f16x8 __attribute__((ext_vector_type(8)));
typedef float f32x4 __attribute__((ext_vector_type(4)));

static __device__ __forceinline__ float lo16(unsigned u) {
  return __half2float(__ushort_as_half((unsigned short)(u & 0xFFFFu)));
}
static __device__ __forceinline__ float hi16(unsigned u) {
  return __half2float(__ushort_as_half((unsigned short)(u >> 16)));
}
static __device__ __forceinline__ unsigned pack16(float a, float b) {
  return (unsigned)__half_as_ushort(__float2half(a)) |
         ((unsigned)__half_as_ushort(__float2half(b)) << 16);
}

// Merged prep phase A. blocks 0..2: fused fp16 weights per layer.
// blocks 3..: edge bucketing into block-private qbuf + fp32->fp16 convert.
__global__ __launch_bounds__(256) void bucket_kernel(
    const float* __restrict__ Wm0, const float* __restrict__ bm0, const float* __restrict__ Wu0,
    const float* __restrict__ Wm1, const float* __restrict__ bm1, const float* __restrict__ Wu1,
    const float* __restrict__ Wm2, const float* __restrict__ bm2, const float* __restrict__ Wu2,
    unsigned short* __restrict__ Wtb, float* __restrict__ dv, int* __restrict__ ovfcnt,
    const float* __restrict__ x, unsigned* __restrict__ xb2, int nquads,
    const int* __restrict__ src, const int* __restrict__ dst,
    unsigned* __restrict__ qbuf, unsigned short* __restrict__ hdr,
    int Epairs, int NP) {
  __shared__ float smem[12288];  // fuse: 3x4096 f32; bucket: 768 ints
  const int t = threadIdx.x;
  if (blockIdx.x < 3) {
    const int l = blockIdx.x;
    const float* Wm = l == 0 ? Wm0 : l == 1 ? Wm1 : Wm2;
    const float* bm = l == 0 ? bm0 : l == 1 ? bm1 : bm2;
    const float* Wu = l == 0 ? Wu0 : l == 1 ? Wu1 : Wu2;
    float* sWm = smem;
    float* sWu = smem + 4096;   // top half of Wu (rows 0..63)
    float* sW1 = smem + 8192;   // Wm @ Wu_top
    for (int i = t; i < 4096; i += 256) {
      sWm[i] = Wm[i];
      sWu[i] = Wu[i];
    }
    __syncthreads();
    for (int i = t; i < 4096; i += 256) {
      const int r = i >> 6, c = i & 63;
      float acc = 0.f;
#pragma unroll
      for (int k = 0; k < 64; ++k) acc = fmaf(sWm[r * 64 + k], sWu[k * 64 + c], acc);
      sW1[i] = acc;
    }
    __syncthreads();
    unsigned short* Wl = Wtb + (size_t)l * 8192;
    for (int i = t; i < 8192; i += 256) {
      const int ncol = i >> 7, k = i & 127;
      const float v = (k < 64) ? sW1[k * 64 + ncol] : Wu[k * 64 + ncol];
      Wl[i] = __half_as_ushort(__float2half(v));
    }
    if (t < 64) {
      float acc = 0.f;
#pragma unroll
      for (int k = 0; k < 64; ++k) acc = fmaf(bm[k], sWu[k * 64 + t], acc);
      dv[l * 64 + t] = acc;
    }
    return;
  }
  const int b = blockIdx.x - 3;
  if (b == 0 && t == 0) *ovfcnt = 0;
  const int gsz = (gridDim.x - 3) * 256;
  for (int i = b * 256 + t; i < nquads; i += gsz) {
    const float4 v = ((const float4*)x)[i];
    xb2[2 * i] = pack16(v.x, v.y);
    xb2[2 * i + 1] = pack16(v.z, v.w);
  }
  int* hist = (int*)smem;
  int* pref = hist + 256;
  int* sc = hist + 512;
  hist[t] = 0;
  __syncthreads();
  unsigned rec[14];
  int pr[14];
  const int base = b * PAIRS_PER_BLK;
#pragma unroll
  for (int k = 0; k < 7; ++k) {
    const int g = base + k * 256 + t;
    if (g < Epairs) {
      const int2 d2 = ((const int2*)dst)[g];
      const int2 s2 = ((const int2*)src)[g];
      const int p0 = d2.x >> 8;
      const int r0 = atomicAdd(&hist[p0], 1);
      pr[2 * k] = (p0 << 16) | r0;
      rec[2 * k] = ((unsigned)d2.x << 16) | (unsigned)(s2.x & 0xFFFF);
      const int p1 = d2.y >> 8;
      const int r1 = atomicAdd(&hist[p1], 1);
      pr[2 * k + 1] = (p1 << 16) | r1;
      rec[2 * k + 1] = ((unsigned)d2.y << 16) | (unsigned)(s2.y & 0xFFFF);
    } else {
      pr[2 * k] = -1;
      pr[2 * k + 1] = -1;
      rec[2 * k] = 0;
      rec[2 * k + 1] = 0;
    }
  }
  __syncthreads();
  const int myc = hist[t];
  sc[t] = myc;
  __syncthreads();
  for (int off = 1; off < 256; off <<= 1) {
    const int u = (t >= off) ? sc[t - off] : 0;
    __syncthreads();
    sc[t] += u;
    __syncthreads();
  }
  pref[t] = sc[t] - myc;  // exclusive prefix
  if (t < NP) hdr[(size_t)b * HDRW + t] = (unsigned short)pref[t];
  if (t == NP - 1) hdr[(size_t)b * HDRW + NP] = (unsigned short)sc[t];
  __syncthreads();
  unsigned* myq = qbuf + (size_t)b * EDGES_PER_BLK;
#pragma unroll
  for (int k = 0; k < 14; ++k) {
    if (pr[k] >= 0) myq[pref[pr[k] >> 16] + (pr[k] & 0xFFFF)] = rec[k];
  }
}

// Phase B: block p owns nodes [p*256, p*256+256): LDS cursors, no global
// atomics, every slab line written by exactly one block (one XCD).
__global__ __launch_bounds__(256) void fill_kernel(
    const unsigned* __restrict__ qbuf, const unsigned short* __restrict__ hdr,
    unsigned short* __restrict__ slab, unsigned* __restrict__ ovf,
    int* __restrict__ ovfcnt, int nblocksA, int n, int Ecap) {
  __shared__ int cur[256];
  const int p = blockIdx.x;
  const int t = threadIdx.x;
  cur[t] = 0;
  __syncthreads();
  for (int sb = t; sb < nblocksA; sb += 256) {
    const int s = hdr[(size_t)sb * HDRW + p];
    const int e = hdr[(size_t)sb * HDRW + p + 1];
    const unsigned* q = qbuf + (size_t)sb * EDGES_PER_BLK;
    for (int i = s; i < e; ++i) {
      const unsigned rec = q[i];
      const int d = rec >> 16;
      const int slot = atomicAdd(&cur[d & (PN - 1)], 1);
      if (slot < 62) {
        slab[(unsigned)d * 64 + 2 + slot] = (unsigned short)(rec & 0xFFFF);
      } else {
        const int o = atomicAdd(ovfcnt, 1);
        if (o < Ecap) ovf[o] = rec;
      }
    }
  }
  __syncthreads();
  const int node = p * PN + t;
  if (node < n) *(int*)(slab + (size_t)node * 64) = cur[t];
}

// One wave per node. Quarter-wave q picks its neighbor via ONE ds_bpermute
// (lane = i + q); 16 lanes x uint2 (8B) = one 128B fp16 row -> 4 neighbor
// rows per load. fp16 data, fp32 accumulation. All bpermutes execute with
// full EXEC (source-lane-active requirement); only the consume is divergent.
#define GRP(VA)                                                      \
  {                                                                  \
    const int s = __builtin_amdgcn_ds_bpermute((VA), myi);           \
    const uint2 u = xu2[(unsigned)s * 16 + j16];                     \
    a0 += lo16(u.x); a1 += hi16(u.x);                                \
    a2 += lo16(u.y); a3 += hi16(u.y);                                \
  }
#define GRPB(VA)                                                     \
  {                                                                  \
    const int s = __builtin_amdgcn_ds_bpermute((VA), myi);           \
    const uint2 u = xu2[(unsigned)s * 16 + j16];                     \
    b0 += lo16(u.x); b1 += hi16(u.x);                                \
    b2 += lo16(u.y); b3 += hi16(u.y);                                \
  }

__global__ __launch_bounds__(256, 8) void gather_kernel(
    const unsigned* __restrict__ xu,   // fp16 x, 32 uints/row
    const unsigned short* __restrict__ slab,
    const unsigned* __restrict__ ovf, const int* __restrict__ ovfcnt,
    unsigned* __restrict__ hxu, int n) {
  const int lane = threadIdx.x & 63;
  const int q = lane >> 4, j16 = lane & 15;
  const uint2* xu2 = (const uint2*)xu;
  uint2* hxu2 = (uint2*)hxu;
  const int ocnt = *ovfcnt;  // 0 in practice; uniform scalar
  const int wid = (blockIdx.x * 256 + threadIdx.x) >> 6;
  const int nwaves = (gridDim.x * 256) >> 6;
  for (int node = wid; node < n; node += nwaves) {
    const int nodeu = __builtin_amdgcn_readfirstlane(node);
    // deg and index loads issue back-to-back (index load is unconditional;
    // lanes >= deg hold garbage that is only bpermuted into discarded lanes).
    const int cnt = *(const int*)(slab + (unsigned)nodeu * 64);
    const int myi = (int)slab[(unsigned)nodeu * 64 + 2 + lane];
    const int c62 = cnt > 62 ? 62 : cnt;
    float a0 = 0.f, a1 = 0.f, a2 = 0.f, a3 = 0.f;
    float b0 = 0.f, b1 = 0.f, b2 = 0.f, b3 = 0.f;
    int va = q << 2;  // bpermute byte addr: lane (i + q)
    int i = 0;
    for (; i + 15 < c62; i += 16) {  // 4 loads in flight, 16 neighbors
      GRP(va)
      GRPB(va + 16)
      GRP(va + 32)
      GRPB(va + 48)
      va += 64;
    }
    for (; i + 3 < c62; i += 4) {
      GRP(va)
      va += 16;
    }
    const int rem = c62 - i;  // wave-uniform
    if (rem > 0) {
      // bpermute with FULL exec (source lanes i..i+rem-1 must be active);
      // only quarters q < rem consume the value.
      const int s = __builtin_amdgcn_ds_bpermute(va, myi);
      if (q < rem) {
        const uint2 u = xu2[(unsigned)s * 16 + j16];
        a0 += lo16(u.x); a1 += hi16(u.x);
        a2 += lo16(u.y); a3 += hi16(u.y);
      }
    }
    if (ocnt) {  // overflow edges (~never)
      for (int e = 0; e < ocnt; ++e) {
        const unsigned v = ovf[e];
        if ((int)(v >> 16) == nodeu && q == 0) {
          const uint2 u = xu2[(v & 0xFFFFu) * 16 + j16];
          a0 += lo16(u.x); a1 += hi16(u.x);
          a2 += lo16(u.y); a3 += hi16(u.y);
        }
      }
    }
    if (q == 0) {  // self row
      const uint2 u = xu2[(unsigned)nodeu * 16 + j16];
      a0 += lo16(u.x); a1 += hi16(u.x);
      a2 += lo16(u.y); a3 += hi16(u.y);
    }
    a0 += b0; a1 += b1; a2 += b2; a3 += b3;
    a0 += __shfl_xor(a0, 16, 64); a0 += __shfl_xor(a0, 32, 64);
    a1 += __shfl_xor(a1, 16, 64); a1 += __shfl_xor(a1, 32, 64);
    a2 += __shfl_xor(a2, 16, 64); a2 += __shfl_xor(a2, 32, 64);
    a3 += __shfl_xor(a3, 16, 64); a3 += __shfl_xor(a3, 32, 64);
    if (q == 0)
      hxu2[(unsigned)nodeu * 16 + j16] = make_uint2(pack16(a0, a1), pack16(a2, a3));
  }
}

// 64 rows per block (4 waves x 16). A = [hx | x] (K=128) staged in swizzled
// LDS; B = Wt[n][k] fragments loaded as contiguous 16B; 16 MFMAs per wave.
// deg for the epilogue comes from the embedded slab cursor.
template <int OUT_F32>
__global__ __launch_bounds__(256) void gemm_kernel(
    const unsigned short* __restrict__ hxb, const unsigned short* __restrict__ xb,
    const unsigned short* __restrict__ Wtb, const float* __restrict__ bu,
    const float* __restrict__ dvec, const unsigned short* __restrict__ slab,
    void* __restrict__ outp, int n) {
  __shared__ unsigned short lhx[64 * 64];
  __shared__ unsigned short lx[64 * 64];
  const int tid = threadIdx.x;
  const int base = blockIdx.x * 64;
  {
    const uint4* ghx = (const uint4*)hxb;
    const uint4* gx = (const uint4*)xb;
    uint4* shx = (uint4*)lhx;
    uint4* sx = (uint4*)lx;
    for (int t = tid; t < 512; t += 256) {
      const int row = t >> 3, c = t & 7;
      const int grow = base + row;
      uint4 vh = make_uint4(0, 0, 0, 0), vx = make_uint4(0, 0, 0, 0);
      if (grow < n) {
        vh = ghx[(size_t)grow * 8 + c];
        vx = gx[(size_t)grow * 8 + c];
      }
      const int cs = c ^ (row & 7);
      shx[row * 8 + cs] = vh;
      sx[row * 8 + cs] = vx;
    }
  }
  const int lane = tid & 63;
  const int w = tid >> 6;
  const int l15 = lane & 15, lg = lane >> 4;
  f16x8 bfr[16];
#pragma unroll
  for (int ct = 0; ct < 4; ++ct)
#pragma unroll
    for (int kq = 0; kq < 4; ++kq)
      bfr[ct * 4 + kq] = *(const f16x8*)((const char*)Wtb + (ct * 16 + l15) * 256 + kq * 64 + lg * 16);
  __syncthreads();
  f32x4 acc[4] = {0, 0, 0, 0};
  const int rt = w * 16 + l15;
#pragma unroll
  for (int kq = 0; kq < 4; ++kq) {
    const unsigned short* mat = (kq < 2) ? lhx : lx;
    const int chunk = lg + 4 * (kq & 1);
    const int cs = chunk ^ (rt & 7);
    const f16x8 af = *(const f16x8*)((const char*)mat + rt * 128 + cs * 16);
#pragma unroll
    for (int ct = 0; ct < 4; ++ct)
      acc[ct] = __builtin_amdgcn_mfma_f32_16x16x32_f16(af, bfr[ct * 4 + kq], acc[ct], 0, 0, 0);
  }
#pragma unroll
  for (int r = 0; r < 4; ++r) {
    const int row = base + w * 16 + lg * 4 + r;
    if (row < n) {
      const float dg = (float)(*(const int*)(slab + (unsigned)row * 64) + 1);
#pragma unroll
      for (int ct = 0; ct < 4; ++ct) {
        const int col = ct * 16 + l15;
        float v = acc[ct][r] + bu[col] + dg * dvec[col];
        v = v > 0.f ? v : 0.f;
        if (OUT_F32)
          ((float*)outp)[(size_t)row * 64 + col] = v;
        else
          ((unsigned short*)outp)[(size_t)row * 64 + col] = __half_as_ushort(__float2half(v));
      }
    }
  }
}

extern "C" void kernel_launch(void* const* d_in, const int* in_sizes, int n_in,
                              void* d_out, int out_size, void* d_ws, size_t ws_size,
                              hipStream_t stream) {
  const float* x = (const float*)d_in[0];
  const int* ei = (const int*)d_in[1];
  const int n = in_sizes[0] / DIM;   // 50000
  const int E = in_sizes[1] / 2;     // 800000
  const int* srcp = ei;
  const int* dstp = ei + E;
  const int Epairs = E / 2;
  const int NP = (n + PN - 1) / PN;                                   // 196
  const int nblocksA = (Epairs + PAIRS_PER_BLK - 1) / PAIRS_PER_BLK;  // 224
  const int Ecap = E / 4;

  // Workspace layout (16B alignment maintained; n%4==0, E even)
  unsigned short* xb = (unsigned short*)d_ws;        // n*64 fp16
  unsigned short* hxb = xb + (size_t)n * DIM;        // n*64 fp16
  unsigned short* yb = hxb + (size_t)n * DIM;        // n*64 fp16
  unsigned short* Wtb = yb + (size_t)n * DIM;        // 3*8192 fp16
  unsigned short* slab = Wtb + 3 * 8192;             // n*64 ushort + 64 pad
  float* dv = (float*)(slab + (size_t)n * DIM + 64); // 3*64
  int* ovfcnt = (int*)(dv + 3 * 64);                 // 1 (+3 pad)
  unsigned* ovf = (unsigned*)(ovfcnt + 4);           // Ecap
  unsigned* qbuf = ovf + Ecap;                       // nblocksA*EDGES_PER_BLK
  unsigned short* hdr = (unsigned short*)(qbuf + (size_t)nblocksA * EDGES_PER_BLK);  // nblocksA*HDRW

  // Prep: (fuse weights || bucket+convert) merged; then fill.
  const int nquads = n * DIM / 4;
  bucket_kernel<<<nblocksA + 3, 256, 0, stream>>>(
      (const float*)d_in[2], (const float*)d_in[3], (const float*)d_in[4],
      (const float*)d_in[6], (const float*)d_in[7], (const float*)d_in[8],
      (const float*)d_in[10], (const float*)d_in[11], (const float*)d_in[12],
      Wtb, dv, ovfcnt, x, (unsigned*)xb, nquads, srcp, dstp, qbuf, hdr, Epairs, NP);
  fill_kernel<<<NP, 256, 0, stream>>>(qbuf, hdr, slab, ovf, ovfcnt, nblocksA, n, Ecap);

  // Layer chain (fp16): xb -> yb -> xb -> d_out(fp32)
  const int gblocks = (n + 63) / 64;
  gather_kernel<<<2048, 256, 0, stream>>>((const unsigned*)xb, slab, ovf, ovfcnt, (unsigned*)hxb, n);
  gemm_kernel<0><<<gblocks, 256, 0, stream>>>(hxb, xb, Wtb, (const float*)d_in[5], dv, slab, yb, n);
  gather_kernel<<<2048, 256, 0, stream>>>((const unsigned*)yb, slab, ovf, ovfcnt, (unsigned*)hxb, n);
  gemm_kernel<0><<<gblocks, 256, 0, stream>>>(hxb, yb, Wtb + 8192, (const float*)d_in[9], dv + 64, slab, xb, n);
  gather_kernel<<<2048, 256, 0, stream>>>((const unsigned*)xb, slab, ovf, ovfcnt, (unsigned*)hxb, n);
  gemm_kernel<1><<<gblocks, 256, 0, stream>>>(hxb, xb, Wtb + 16384, (const float*)d_in[13], dv + 128, slab, d_out, n);
}